// Round 12
// baseline (98.835 us; speedup 1.0000x reference)
//
#include <hip/hip_runtime.h>
#include <hip/hip_fp16.h>

// Clang native vector types — required by __builtin_nontemporal_* (HIP's
// float4/int4 are classes, which the builtin rejects).
typedef float vf4 __attribute__((ext_vector_type(4)));
typedef int   vi4 __attribute__((ext_vector_type(4)));

// Packed node record: path-segment sum s and jump pointer p in 8 bytes,
// so each random gather touches exactly one cache line.
struct SP { float s; int p; };

__device__ __forceinline__ SP ldSP(const SP* __restrict__ ptr) {
    float2 v = *reinterpret_cast<const float2*>(ptr);
    SP r; r.s = v.x; r.p = __float_as_int(v.y);
    return r;
}
__device__ __forceinline__ void stSP(SP* __restrict__ ptr, float s, int p) {
    float2 v; v.x = s; v.y = __int_as_float(p);
    *reinterpret_cast<float2*>(ptr) = v;
}

// contrib[i] = sigmoid(attrs[i]·w + b) * (levels[i] - levels[parent]);
// root = levels[0] with sentinel p=N. attrs/parent are one-shot streams ->
// nontemporal. levels[i] is coalesced; levels[p] random over 8 MB (L2/L3).
__global__ void k_contrib(const float* __restrict__ attrs,
                          const float* __restrict__ weight,
                          const float* __restrict__ bias,
                          const float* __restrict__ levels,
                          const int*   __restrict__ parent,
                          SP* __restrict__ buf, int N) {
    float w0 = weight[0], w1 = weight[1], w2 = weight[2], w3 = weight[3];
    float w4 = weight[4], w5 = weight[5], w6 = weight[6], w7 = weight[7];
    float b = bias[0];
    int stride = gridDim.x * blockDim.x;
    const vf4* a4 = reinterpret_cast<const vf4*>(attrs);
    for (int i = blockIdx.x * blockDim.x + threadIdx.x; i < N; i += stride) {
        vf4 a0 = __builtin_nontemporal_load(&a4[2 * (size_t)i]);
        vf4 a1 = __builtin_nontemporal_load(&a4[2 * (size_t)i + 1]);
        float x = a0.x * w0 + a0.y * w1 + a0.z * w2 + a0.w * w3
                + a1.x * w4 + a1.y * w5 + a1.z * w6 + a1.w * w7 + b;
        float sg = 1.0f / (1.0f + __expf(-x));
        int p = __builtin_nontemporal_load(&parent[i]);
        float c = sg * (levels[i] - levels[p]);
        if (i == 0) stSP(&buf[0], levels[0], N);   // root: sentinel parent
        else        stSP(&buf[i], c, p);
    }
}

// Bottom ladder: nodes [0,T) chase the FULL path to the root. Every hop lands
// inside buf[0..T) (4 MB, one XCD's L2 -> hot after first touches); chains are
// fully parallel (one thread per node), wall ~= max-depth x L2 latency.
// Pure f32 accumulation -> exact. Root exits via sentinel p=N.
__global__ void k_lbot(const SP* __restrict__ buf,
                       __half* __restrict__ y16, int T, int N) {
    int i = blockIdx.x * blockDim.x + threadIdx.x;
    if (i >= T) return;
    float acc = 0.0f;
    int p = i;                       // first read coalesced
    while (p < N) {                  // only the root record has p = N
        SP w = ldSP(&buf[p]);
        acc += w.s;
        p = w.p;
    }
    y16[i] = __float2half(acc);
}

// Top ladder: nodes [T,N) chase while p >= T (index shrinks ~e x per hop,
// ~1.2M total random hops over the 12 MB top region), then add the exact
// bottom sum y16[p] (1 MB slice, L2-hot). One f16 rounding total.
__global__ void k_ltop(const SP* __restrict__ buf,
                       __half* __restrict__ y16, int T, int N) {
    int i = T + blockIdx.x * blockDim.x + threadIdx.x;
    if (i >= N) return;
    float acc = 0.0f;
    int p = i;                       // first read coalesced
    while (p >= T) {                 // strictly decreasing -> crosses T, never
        SP w = ldSP(&buf[p]);        // reaches the sentinel
        acc += w.s;
        p = w.p;
    }
    y16[i] = __float2half(acc + __half2float(y16[p]));
}

// out[pixel] = y16[pixel_node[pixel]]. pix/out are pure streams ->
// nontemporal; y16 (4 MB) takes its chances in L2 (R10/R11 showed slice
// phasing and stream bypass are both neutral here).
__global__ void k_gather(const __half* __restrict__ y,
                         const int*   __restrict__ pix,
                         float*       __restrict__ out, int M) {
    int stride = gridDim.x * blockDim.x;
    int M4 = M >> 2;
    const vi4* pix4 = reinterpret_cast<const vi4*>(pix);
    vf4* out4 = reinterpret_cast<vf4*>(out);
    for (int i = blockIdx.x * blockDim.x + threadIdx.x; i < M4; i += stride) {
        vi4 p = __builtin_nontemporal_load(&pix4[i]);
        vf4 o;
        o.x = __half2float(y[p.x]);
        o.y = __half2float(y[p.y]);
        o.z = __half2float(y[p.z]);
        o.w = __half2float(y[p.w]);
        __builtin_nontemporal_store(o, &out4[i]);
    }
    int tid = blockIdx.x * blockDim.x + threadIdx.x;
    for (int i = (M4 << 2) + tid; i < M; i += stride)
        out[i] = __half2float(y[pix[i]]);
}

extern "C" void kernel_launch(void* const* d_in, const int* in_sizes, int n_in,
                              void* d_out, int out_size, void* d_ws, size_t ws_size,
                              hipStream_t stream) {
    const float* attrs  = (const float*)d_in[0];
    const float* weight = (const float*)d_in[1];
    const float* bias   = (const float*)d_in[2];
    const float* levels = (const float*)d_in[3];
    const int*   parent = (const int*)d_in[4];
    const int*   pix    = (const int*)d_in[5];
    float* out = (float*)d_out;

    const int N = in_sizes[3];     // 2,000,000 nodes
    const int M = out_size;        // H*W pixels

    SP*     buf = (SP*)d_ws;               // 16 MB packed {contrib, parent}
    __half* y16 = (__half*)(buf + N);      //  4 MB node outputs (fp16)

    const int BLK = 256;
    const int T = 524288;                  // bottom region: 4 MB of buf
    #define CDIV(a,b) (((a)+(b)-1)/(b))

    k_contrib<<<2048, BLK, 0, stream>>>(attrs, weight, bias, levels, parent, buf, N);
    k_lbot <<<CDIV(T,     BLK), BLK, 0, stream>>>(buf, y16, T, N);
    k_ltop <<<CDIV(N - T, BLK), BLK, 0, stream>>>(buf, y16, T, N);
    k_gather<<<2048, BLK, 0, stream>>>(y16, pix, out, M);
}

// Round 13
// 93.344 us; speedup vs baseline: 1.0588x; 1.0588x over previous
//
#include <hip/hip_runtime.h>
#include <hip/hip_fp16.h>

// Clang native vector types — required by __builtin_nontemporal_* (HIP's
// float4/int4 are classes, which the builtin rejects).
typedef float vf4 __attribute__((ext_vector_type(4)));
typedef int   vi4 __attribute__((ext_vector_type(4)));

// Packed node record: path-segment sum s and jump pointer p in 8 bytes,
// so each random hop touches exactly one cache line.
struct SP { float s; int p; };

__device__ __forceinline__ SP ldSP(const SP* __restrict__ ptr) {
    float2 v = *reinterpret_cast<const float2*>(ptr);
    SP r; r.s = v.x; r.p = __float_as_int(v.y);
    return r;
}
__device__ __forceinline__ void stSP(SP* __restrict__ ptr, float s, int p) {
    float2 v; v.x = s; v.y = __int_as_float(p);
    *reinterpret_cast<float2*>(ptr) = v;
}

// contrib[i] = sigmoid(attrs[i]·w + b) * (levels[i] - levels[parent]);
// root = levels[0] with sentinel p=N. attrs/parent are one-shot streams ->
// nontemporal. levels[i] coalesced; levels[p] random over 8 MB (L3-resident).
__global__ void k_contrib(const float* __restrict__ attrs,
                          const float* __restrict__ weight,
                          const float* __restrict__ bias,
                          const float* __restrict__ levels,
                          const int*   __restrict__ parent,
                          SP* __restrict__ buf, int N) {
    float w0 = weight[0], w1 = weight[1], w2 = weight[2], w3 = weight[3];
    float w4 = weight[4], w5 = weight[5], w6 = weight[6], w7 = weight[7];
    float b = bias[0];
    int stride = gridDim.x * blockDim.x;
    const vf4* a4 = reinterpret_cast<const vf4*>(attrs);
    for (int i = blockIdx.x * blockDim.x + threadIdx.x; i < N; i += stride) {
        vf4 a0 = __builtin_nontemporal_load(&a4[2 * (size_t)i]);
        vf4 a1 = __builtin_nontemporal_load(&a4[2 * (size_t)i + 1]);
        float x = a0.x * w0 + a0.y * w1 + a0.z * w2 + a0.w * w3
                + a1.x * w4 + a1.y * w5 + a1.z * w6 + a1.w * w7 + b;
        float sg = 1.0f / (1.0f + __expf(-x));
        int p = __builtin_nontemporal_load(&parent[i]);
        float c = sg * (levels[i] - levels[p]);
        if (i == 0) stSP(&buf[0], levels[0], N);   // root: sentinel parent
        else        stSP(&buf[i], c, p);
    }
}

// One ladder level [lo,hi): chase while the chain stays >= lo (parent index
// shrinks ~e x per hop), then add y16 of the already-exact lower levels
// (region <= lo*2 bytes, L2-resident). Bottom level (lo=0) exits only via the
// root sentinel p=N. fp16 rounding chains once per LEVEL, not per tree edge.
// Correct for any tree depth. Level splits chosen to minimize total random
// hops (~2.3M): R9 (finer) and R12 (coarser) both measured worse.
__global__ void k_level(const SP* __restrict__ buf,
                        __half* __restrict__ y16,
                        int lo, int hi, int N) {
    int i = lo + blockIdx.x * blockDim.x + threadIdx.x;
    if (i >= hi) return;
    float acc = 0.0f;
    int p = i;                       // first read coalesced
    while (p >= lo && p < N) {
        SP w = ldSP(&buf[p]);
        acc += w.s;
        p = w.p;
    }
    if (p < lo) acc += __half2float(y16[p]);
    y16[i] = __float2half(acc);
}

// out[pixel] = y16[pixel_node[pixel]]. pix/out are pure streams ->
// nontemporal. Residency experiments (R10 slice-phasing, R11 sc1-nt bypass)
// were both neutral: the gather sits at the machine's scattered-request
// floor, so keep the simplest form.
__global__ void k_gather(const __half* __restrict__ y,
                         const int*   __restrict__ pix,
                         float*       __restrict__ out, int M) {
    int stride = gridDim.x * blockDim.x;
    int M4 = M >> 2;
    const vi4* pix4 = reinterpret_cast<const vi4*>(pix);
    vf4* out4 = reinterpret_cast<vf4*>(out);
    for (int i = blockIdx.x * blockDim.x + threadIdx.x; i < M4; i += stride) {
        vi4 p = __builtin_nontemporal_load(&pix4[i]);
        vf4 o;
        o.x = __half2float(y[p.x]);
        o.y = __half2float(y[p.y]);
        o.z = __half2float(y[p.z]);
        o.w = __half2float(y[p.w]);
        __builtin_nontemporal_store(o, &out4[i]);
    }
    int tid = blockIdx.x * blockDim.x + threadIdx.x;
    for (int i = (M4 << 2) + tid; i < M; i += stride)
        out[i] = __half2float(y[pix[i]]);
}

extern "C" void kernel_launch(void* const* d_in, const int* in_sizes, int n_in,
                              void* d_out, int out_size, void* d_ws, size_t ws_size,
                              hipStream_t stream) {
    const float* attrs  = (const float*)d_in[0];
    const float* weight = (const float*)d_in[1];
    const float* bias   = (const float*)d_in[2];
    const float* levels = (const float*)d_in[3];
    const int*   parent = (const int*)d_in[4];
    const int*   pix    = (const int*)d_in[5];
    float* out = (float*)d_out;

    const int N = in_sizes[3];     // 2,000,000 nodes
    const int M = out_size;        // H*W pixels

    SP*     buf = (SP*)d_ws;               // 16 MB packed {contrib, parent}
    __half* y16 = (__half*)(buf + N);      //  4 MB node outputs (fp16)

    const int BLK = 256;
    #define CDIV(a,b) (((a)+(b)-1)/(b))

    k_contrib<<<2048, BLK, 0, stream>>>(attrs, weight, bias, levels, parent, buf, N);

    // Geometric ladder, bottom-up (R7's hop-minimal 4-level split).
    const int T1 = 32768, T2 = 524288, T3 = 1048576;
    k_level<<<CDIV(T1,      BLK), BLK, 0, stream>>>(buf, y16, 0,  T1, N);
    k_level<<<CDIV(T2 - T1, BLK), BLK, 0, stream>>>(buf, y16, T1, T2, N);
    k_level<<<CDIV(T3 - T2, BLK), BLK, 0, stream>>>(buf, y16, T2, T3, N);
    k_level<<<CDIV(N  - T3, BLK), BLK, 0, stream>>>(buf, y16, T3, N,  N);

    k_gather<<<2048, BLK, 0, stream>>>(y16, pix, out, M);
}

// Round 14
// 90.162 us; speedup vs baseline: 1.0962x; 1.0353x over previous
//
#include <hip/hip_runtime.h>
#include <hip/hip_fp16.h>

// Clang native vector types — required by __builtin_nontemporal_* (HIP's
// float4/int4 are classes, which the builtin rejects).
typedef float vf4 __attribute__((ext_vector_type(4)));
typedef int   vi4 __attribute__((ext_vector_type(4)));

// Packed node record: path-segment sum s and jump pointer p in 8 bytes,
// so each random hop touches exactly one cache line.
struct SP { float s; int p; };

__device__ __forceinline__ SP ldSP(const SP* __restrict__ ptr) {
    float2 v = *reinterpret_cast<const float2*>(ptr);
    SP r; r.s = v.x; r.p = __float_as_int(v.y);
    return r;
}
__device__ __forceinline__ void stSP(SP* __restrict__ ptr, float s, int p) {
    float2 v; v.x = s; v.y = __int_as_float(p);
    *reinterpret_cast<float2*>(ptr) = v;
}

// contrib[i] = sigmoid(attrs[i]·w + b) * (levels[i] - levels[parent]);
// root record overwritten by thread 0 with {levels[0], sentinel N}.
// Exact-sized: one node per thread, no loop. attrs/parent nontemporal.
__global__ void k_contrib(const float* __restrict__ attrs,
                          const float* __restrict__ weight,
                          const float* __restrict__ bias,
                          const float* __restrict__ levels,
                          const int*   __restrict__ parent,
                          SP* __restrict__ buf, int N) {
    int i = blockIdx.x * blockDim.x + threadIdx.x;
    if (i >= N) return;
    float w0 = weight[0], w1 = weight[1], w2 = weight[2], w3 = weight[3];
    float w4 = weight[4], w5 = weight[5], w6 = weight[6], w7 = weight[7];
    float b = bias[0];
    const vf4* a4 = reinterpret_cast<const vf4*>(attrs);
    vf4 a0 = __builtin_nontemporal_load(&a4[2 * (size_t)i]);
    vf4 a1 = __builtin_nontemporal_load(&a4[2 * (size_t)i + 1]);
    float x = a0.x * w0 + a0.y * w1 + a0.z * w2 + a0.w * w3
            + a1.x * w4 + a1.y * w5 + a1.z * w6 + a1.w * w7 + b;
    float sg = 1.0f / (1.0f + __expf(-x));
    int p = __builtin_nontemporal_load(&parent[i]);
    float c = sg * (levels[i] - levels[p]);
    // Branch-free hot path; root fixed by a single re-store (i==0 only).
    stSP(&buf[i], (i == 0) ? levels[0] : c, (i == 0) ? N : p);
}

// One ladder level [lo,hi): chase while the chain stays >= lo (parent index
// shrinks ~e x per hop), then add y16 of the already-exact lower levels
// (region <= lo*2 bytes, L2-resident). Bottom level (lo=0) exits only via the
// root sentinel p=N. fp16 rounding chains once per LEVEL, not per tree edge.
// Correct for any tree depth. R7's 4-level split measured hop-minimal
// (R9 finer: worse by launches; R12 coarser: worse by hops).
__global__ void k_level(const SP* __restrict__ buf,
                        __half* __restrict__ y16,
                        int lo, int hi, int N) {
    int i = lo + blockIdx.x * blockDim.x + threadIdx.x;
    if (i >= hi) return;
    float acc = 0.0f;
    int p = i;                       // first read coalesced
    while (p >= lo && p < N) {
        SP w = ldSP(&buf[p]);
        acc += w.s;
        p = w.p;
    }
    if (p < lo) acc += __half2float(y16[p]);
    y16[i] = __float2half(acc);
}

// out[pixel] = y16[pixel_node[pixel]]. Exact-sized straight-line: one vec4
// of pixels per thread, no loop. pix/out nt-streamed; y16 loads allocate.
// The scattered y16 touches sit at the L3 line-traffic wall (~270 MB of
// 64B-line fills); R10 slice-phasing and R11 L2-bypass both measured null.
__global__ void k_gather(const __half* __restrict__ y,
                         const int*   __restrict__ pix,
                         float*       __restrict__ out, int M) {
    int g = blockIdx.x * blockDim.x + threadIdx.x;
    int M4 = M >> 2;
    if (g < M4) {
        const vi4* pix4 = reinterpret_cast<const vi4*>(pix);
        vf4* out4 = reinterpret_cast<vf4*>(out);
        vi4 p = __builtin_nontemporal_load(&pix4[g]);
        vf4 o;
        o.x = __half2float(y[p.x]);
        o.y = __half2float(y[p.y]);
        o.z = __half2float(y[p.z]);
        o.w = __half2float(y[p.w]);
        __builtin_nontemporal_store(o, &out4[g]);
    }
    // tail (M % 4 != 0): not taken at 2048x2048, kept for generality
    if (g == 0) {
        for (int i = M4 << 2; i < M; ++i)
            out[i] = __half2float(y[pix[i]]);
    }
}

extern "C" void kernel_launch(void* const* d_in, const int* in_sizes, int n_in,
                              void* d_out, int out_size, void* d_ws, size_t ws_size,
                              hipStream_t stream) {
    const float* attrs  = (const float*)d_in[0];
    const float* weight = (const float*)d_in[1];
    const float* bias   = (const float*)d_in[2];
    const float* levels = (const float*)d_in[3];
    const int*   parent = (const int*)d_in[4];
    const int*   pix    = (const int*)d_in[5];
    float* out = (float*)d_out;

    const int N = in_sizes[3];     // 2,000,000 nodes
    const int M = out_size;        // H*W pixels

    SP*     buf = (SP*)d_ws;               // 16 MB packed {contrib, parent}
    __half* y16 = (__half*)(buf + N);      //  4 MB node outputs (fp16)

    const int BLK = 256;
    #define CDIV(a,b) (((a)+(b)-1)/(b))

    k_contrib<<<CDIV(N, BLK), BLK, 0, stream>>>(attrs, weight, bias, levels, parent, buf, N);

    // Geometric ladder, bottom-up (R7's hop-minimal 4-level split).
    const int T1 = 32768, T2 = 524288, T3 = 1048576;
    k_level<<<CDIV(T1,      BLK), BLK, 0, stream>>>(buf, y16, 0,  T1, N);
    k_level<<<CDIV(T2 - T1, BLK), BLK, 0, stream>>>(buf, y16, T1, T2, N);
    k_level<<<CDIV(T3 - T2, BLK), BLK, 0, stream>>>(buf, y16, T2, T3, N);
    k_level<<<CDIV(N  - T3, BLK), BLK, 0, stream>>>(buf, y16, T3, N,  N);

    k_gather<<<CDIV(M / 4, BLK), BLK, 0, stream>>>(y16, pix, out, M);
}